// Round 8
// baseline (120.797 us; speedup 1.0000x reference)
//
#include <hip/hip_runtime.h>

#define NEARZERO 1e-5f
#define RLEN 15
#define LOG2E 1.4426950408889634f

typedef float f32x4 __attribute__((ext_vector_type(4)));
struct __attribute__((packed, aligned(4))) uld4 { f32x4 v; };

static __device__ __forceinline__ f32x4 ld4u(const float* p) {
    return ((const uld4*)p)->v;     // 16B load, 4B-aligned (dwordx4)
}

struct Par { float FC, invFC, invLPFC, K1, K2, PERC, UZL, TT, CFMAX, CFRC, CWH, C; };

#define SB() __builtin_amdgcn_sched_barrier(0)

template<int PH>
__device__ __forceinline__ float one_step(
    float P, float TEMP, float PET, float dx, float dy, float dz,
    const Par& pr,
    float& SNOWPACK, float& MELTWATER, float& SM, float& SUZ, float& SLZ,
    float (&acc)[RLEN], const float (&w)[RLEN])
{
    const float pBETA   = fmaf(dx, 5.0f, 1.0f);
    const float pK0     = fmaf(dy, 0.85f, 0.05f);
    const float pBETAET = fmaf(dz, 4.7f, 0.3f);

    const float d    = TEMP - pr.TT;
    const float RAIN = (d >= 0.0f) ? P : 0.0f;
    const float SNOW = P - RAIN;
    SNOWPACK += SNOW;
    const float melt = __builtin_amdgcn_fmed3f(pr.CFMAX * d, 0.0f, SNOWPACK);
    MELTWATER += melt;
    SNOWPACK  -= melt;
    const float refr = __builtin_amdgcn_fmed3f(pr.CFRC * (0.0f - d), 0.0f, MELTWATER);
    SNOWPACK  += refr;
    MELTWATER -= refr;
    const float tosoil = fmaxf(fmaf(-pr.CWH, SNOWPACK, MELTWATER), 0.0f);
    MELTWATER -= tosoil;

    const float sw = fminf(exp2f(pBETA * __log2f(SM * pr.invFC)), 1.0f);
    const float rt = RAIN + tosoil;
    const float recharge = rt * sw;
    SM = SM + rt - recharge;
    const float excess = fmaxf(SM - pr.FC, 0.0f);
    SM -= excess;
    const float ef = fminf(exp2f(pBETAET * __log2f(SM * pr.invLPFC)), 1.0f);
    const float ETact = fminf(SM, PET * ef);
    SM = fmaxf(SM - ETact, NEARZERO);
    const float capillary = pr.C * SLZ * (1.0f - fminf(SM * pr.invFC, 1.0f));
    SM  = fmaxf(SM + capillary, NEARZERO);
    SLZ = fmaxf(SLZ - capillary, NEARZERO);

    SUZ += recharge + excess;
    const float PERC = fminf(SUZ, pr.PERC);
    SUZ -= PERC;
    const float Q0 = pK0 * fmaxf(SUZ - pr.UZL, 0.0f);
    SUZ -= Q0;
    const float Q1 = pr.K1 * SUZ;
    SUZ -= Q1;
    SLZ += PERC;
    const float Q2 = pr.K2 * SLZ;
    SLZ -= Q2;
    const float Qsim = Q0 + Q1 + Q2;

    // rotating-accumulator FIR (hand-verified): out[t] = acc[t%15] + w0*Q[t]
    const float qr = fmaf(w[0], Qsim, acc[PH]);
    acc[PH] = 0.0f;
#pragma unroll
    for (int k = 1; k < RLEN; ++k) {
        const int j = (PH + k) % RLEN;      // compile-time
        acc[j] = fmaf(w[k], Qsim, acc[j]);
    }
    return qr;
}

template<int PH0>
__device__ __forceinline__ void comp5(
    const f32x4 (&F)[5], const f32x4 (&D)[5], const Par& pr,
    float& SP_, float& MW, float& SM, float& SUZ, float& SLZ,
    float (&acc)[RLEN], const float (&w)[RLEN],
    float*& outp, int G, bool guard)
{
    float qr;
    qr = one_step<(PH0 + 0) % RLEN>(F[0].x, F[0].y, F[0].z, D[0].x, D[0].y, D[0].z,
                                    pr, SP_, MW, SM, SUZ, SLZ, acc, w);
    if (guard) __builtin_nontemporal_store(qr, outp);
    outp += G;
    qr = one_step<(PH0 + 1) % RLEN>(F[1].x, F[1].y, F[1].z, D[1].x, D[1].y, D[1].z,
                                    pr, SP_, MW, SM, SUZ, SLZ, acc, w);
    if (guard) __builtin_nontemporal_store(qr, outp);
    outp += G;
    qr = one_step<(PH0 + 2) % RLEN>(F[2].x, F[2].y, F[2].z, D[2].x, D[2].y, D[2].z,
                                    pr, SP_, MW, SM, SUZ, SLZ, acc, w);
    if (guard) __builtin_nontemporal_store(qr, outp);
    outp += G;
    qr = one_step<(PH0 + 3) % RLEN>(F[3].x, F[3].y, F[3].z, D[3].x, D[3].y, D[3].z,
                                    pr, SP_, MW, SM, SUZ, SLZ, acc, w);
    if (guard) __builtin_nontemporal_store(qr, outp);
    outp += G;
    qr = one_step<(PH0 + 4) % RLEN>(F[4].x, F[4].y, F[4].z, D[4].x, D[4].y, D[4].z,
                                    pr, SP_, MW, SM, SUZ, SLZ, acc, w);
    if (guard) __builtin_nontemporal_store(qr, outp);
    outp += G;
}

__global__ __launch_bounds__(64, 1) void hbv_kernel(
    const float* __restrict__ forcing,   // (365,G,3)
    const float* __restrict__ dynr,      // (365,G,3)
    const float* __restrict__ statr,     // (G,15)
    float* __restrict__ out,             // (365,G)
    int G)
{
    const int lane = threadIdx.x;
    const int g  = blockIdx.x * 64 + lane;
    const int gc = (g < G) ? g : (G - 1);          // clamp for loads; store guarded
    const bool guard = (g < G);

    // ---- static parameters ----
    const float* sp = statr + (size_t)gc * 15;
    Par pr;
    pr.FC    = fmaf(sp[0], 950.0f, 50.0f);
    pr.K1    = fmaf(sp[1], 0.49f, 0.01f);
    pr.K2    = fmaf(sp[2], 0.199f, 0.001f);
    const float parLP = fmaf(sp[3], 0.8f, 0.2f);
    pr.PERC  = sp[4] * 10.0f;
    pr.UZL   = sp[5] * 100.0f;
    pr.TT    = fmaf(sp[6], 5.0f, -2.5f);
    pr.CFMAX = fmaf(sp[7], 9.5f, 0.5f);
    pr.CFRC  = (sp[8] * 0.1f) * pr.CFMAX;
    pr.CWH   = sp[9] * 0.2f;
    pr.C     = sp[10];
    const float rout_a = sp[13] * 2.9f;
    const float rout_b = sp[14] * 6.5f;
    pr.invFC   = 1.0f / pr.FC;
    pr.invLPFC = 1.0f / (parLP * pr.FC);

    // ---- routing weights (Gamma(aa)*theta^aa cancels in normalization) ----
    const float aa    = fmaxf(rout_a, 0.0f) + 0.1f;
    const float theta = fmaxf(rout_b, 0.0f) + 0.5f;
    const float am1   = aa - 1.0f;
    const float nitl2 = -LOG2E / theta;
    float w[RLEN];
    float wsum = 0.0f;
#pragma unroll
    for (int k = 0; k < RLEN; ++k) {
        const float tk = (float)k + 0.5f;
        w[k] = exp2f(am1 * __log2f(tk) + tk * nitl2);
        wsum += w[k];
    }
    const float winv = 1.0f / wsum;
#pragma unroll
    for (int k = 0; k < RLEN; ++k) w[k] *= winv;

    // ---- state ----
    float SP_ = 0.001f, MW = 0.001f, SM = 0.001f, SUZ = 0.001f, SLZ = 0.001f;
    float acc[RLEN];
#pragma unroll
    for (int k = 0; k < RLEN; ++k) acc[k] = 0.0f;

    const size_t sT = (size_t)G * 3;               // floats per time step
    const float* pF = forcing + (size_t)gc * 3;
    const float* pD = dynr    + (size_t)gc * 3;
    float* outp = out + g;

    // ---- 3 rotating 5-step buffers (constexpr indices only) ----
    f32x4 AF[5], AD[5], BF[5], BD[5], CF[5], CD[5];

    // Plain (compiler-visible) vec4 loads: auto-waitcnt counts exactly, so
    // correctness is independent of spills/reorder. sched_barrier(0) fences
    // pin the ISSUE point (the R1 failure was these sinking to their use).
#define LOADG(BFv, BDv, tb) do { \
    const float* fp_ = pF + (size_t)(tb) * sT; \
    const float* dp_ = pD + (size_t)(tb) * sT; \
    BFv[0] = ld4u(fp_); BDv[0] = ld4u(dp_); fp_ += sT; dp_ += sT; \
    BFv[1] = ld4u(fp_); BDv[1] = ld4u(dp_); fp_ += sT; dp_ += sT; \
    BFv[2] = ld4u(fp_); BDv[2] = ld4u(dp_); fp_ += sT; dp_ += sT; \
    BFv[3] = ld4u(fp_); BDv[3] = ld4u(dp_); fp_ += sT; dp_ += sT; \
    BFv[4] = ld4u(fp_); BDv[4] = ld4u(dp_); \
} while (0)

    // prologue: groups 0,1 (steps 0-4, 5-9)
    LOADG(AF, AD, 0);
    LOADG(BF, BD, 5);

    // main: 23 iters x 15 steps = t 0..344.
    // iter i consumes groups 3i,3i+1,3i+2; reloads 3i+2 (C), 3i+3 (A), 3i+4 (B).
    for (int i = 0; i < 23; ++i) {
        const int tb = i * 15;
        SB(); LOADG(CF, CD, tb + 10); SB();
        comp5<0>(AF, AD, pr, SP_, MW, SM, SUZ, SLZ, acc, w, outp, G, guard);
        SB(); LOADG(AF, AD, tb + 15); SB();
        comp5<5>(BF, BD, pr, SP_, MW, SM, SUZ, SLZ, acc, w, outp, G, guard);
        SB(); LOADG(BF, BD, tb + 20); SB();
        comp5<10>(CF, CD, pr, SP_, MW, SM, SUZ, SLZ, acc, w, outp, G, guard);
    }
    // tail: t=345..364 (groups 69..72). Entering: A=g69, B=g70.
    SB(); LOADG(CF, CD, 355); SB();
    comp5<0>(AF, AD, pr, SP_, MW, SM, SUZ, SLZ, acc, w, outp, G, guard);   // 345-349
    SB(); LOADG(AF, AD, 360); SB();
    comp5<5>(BF, BD, pr, SP_, MW, SM, SUZ, SLZ, acc, w, outp, G, guard);   // 350-354
    comp5<10>(CF, CD, pr, SP_, MW, SM, SUZ, SLZ, acc, w, outp, G, guard);  // 355-359
    comp5<0>(AF, AD, pr, SP_, MW, SM, SUZ, SLZ, acc, w, outp, G, guard);   // 360-364
#undef LOADG
}

extern "C" void kernel_launch(void* const* d_in, const int* in_sizes, int n_in,
                              void* d_out, int out_size, void* d_ws, size_t ws_size,
                              hipStream_t stream) {
    const float* forcing = (const float*)d_in[0];
    const float* dynr    = (const float*)d_in[1];
    const float* statr   = (const float*)d_in[2];
    float* out = (float*)d_out;

    const int G = in_sizes[2] / 15;          // static_raw (G,15); T fixed at 365
    const int block = 64;
    const int grid  = (G + block - 1) / block;
    hbv_kernel<<<grid, block, 0, stream>>>(forcing, dynr, statr, out, G);
}

// Round 9
// 111.239 us; speedup vs baseline: 1.0859x; 1.0859x over previous
//
#include <hip/hip_runtime.h>

#define NEARZERO 1e-5f
#define RLEN 15
#define LOG2E 1.4426950408889634f

struct __attribute__((packed, aligned(4))) F3 { float x, y, z; };

static __device__ __forceinline__ F3 ld3f(const float* p) {
    return *reinterpret_cast<const F3*>(p);   // dwordx3-class load
}

struct Par { float FC, invFC, invLPFC, K1, K2, PERC, UZL, TT, CFMAX, CFRC, CWH, C; };

template<int PH>
__device__ __forceinline__ float one_step(
    float P, float TEMP, float PET, float dx, float dy, float dz,
    const Par& pr,
    float& SNOWPACK, float& MELTWATER, float& SM, float& SUZ, float& SLZ,
    float (&acc)[RLEN], const float (&w)[RLEN])
{
    const float pBETA   = fmaf(dx, 5.0f, 1.0f);
    const float pK0     = fmaf(dy, 0.85f, 0.05f);
    const float pBETAET = fmaf(dz, 4.7f, 0.3f);

    const float d    = TEMP - pr.TT;
    const float RAIN = (d >= 0.0f) ? P : 0.0f;
    const float SNOW = P - RAIN;
    SNOWPACK += SNOW;
    const float melt = __builtin_amdgcn_fmed3f(pr.CFMAX * d, 0.0f, SNOWPACK);
    MELTWATER += melt;
    SNOWPACK  -= melt;
    const float refr = __builtin_amdgcn_fmed3f(pr.CFRC * (0.0f - d), 0.0f, MELTWATER);
    SNOWPACK  += refr;
    MELTWATER -= refr;
    const float tosoil = fmaxf(fmaf(-pr.CWH, SNOWPACK, MELTWATER), 0.0f);
    MELTWATER -= tosoil;

    const float sw = fminf(exp2f(pBETA * __log2f(SM * pr.invFC)), 1.0f);
    const float rt = RAIN + tosoil;
    const float recharge = rt * sw;
    SM = SM + rt - recharge;
    const float excess = fmaxf(SM - pr.FC, 0.0f);
    SM -= excess;
    const float ef = fminf(exp2f(pBETAET * __log2f(SM * pr.invLPFC)), 1.0f);
    const float ETact = fminf(SM, PET * ef);
    SM = fmaxf(SM - ETact, NEARZERO);
    const float capillary = pr.C * SLZ * (1.0f - fminf(SM * pr.invFC, 1.0f));
    SM  = fmaxf(SM + capillary, NEARZERO);
    SLZ = fmaxf(SLZ - capillary, NEARZERO);

    SUZ += recharge + excess;
    const float PERC = fminf(SUZ, pr.PERC);
    SUZ -= PERC;
    const float Q0 = pK0 * fmaxf(SUZ - pr.UZL, 0.0f);
    SUZ -= Q0;
    const float Q1 = pr.K1 * SUZ;
    SUZ -= Q1;
    SLZ += PERC;
    const float Q2 = pr.K2 * SLZ;
    SLZ -= Q2;
    const float Qsim = Q0 + Q1 + Q2;

    // rotating-accumulator FIR: out[t] = acc[t%15] + w0*Q[t]
    const float qr = fmaf(w[0], Qsim, acc[PH]);
    acc[PH] = 0.0f;
#pragma unroll
    for (int k = 1; k < RLEN; ++k) {
        const int j = (PH + k) % RLEN;      // compile-time
        acc[j] = fmaf(w[k], Qsim, acc[j]);
    }
    return qr;
}

__global__ __launch_bounds__(64, 1) void hbv_kernel(
    const float* __restrict__ forcing,   // (365,G,3)
    const float* __restrict__ dynr,      // (365,G,3)
    const float* __restrict__ statr,     // (G,15)
    float* __restrict__ out,             // (365,G)
    int G)
{
    const int lane = threadIdx.x;
    const int g  = blockIdx.x * 64 + lane;
    const int gc = (g < G) ? g : (G - 1);          // clamp for loads; store guarded
    const bool guard = (g < G);

    // LDS ring: [slot][lane][P,T,PET,dx,dy,dz]. One wave per block -> no barriers.
    // Bank map: dword addr = lane*6 + c -> 2-way aliasing only (free, m136).
    __shared__ float ring[RLEN][64][6];            // 23040 B

    // ---- static parameters ----
    const float* sp = statr + (size_t)gc * 15;
    Par pr;
    pr.FC    = fmaf(sp[0], 950.0f, 50.0f);
    pr.K1    = fmaf(sp[1], 0.49f, 0.01f);
    pr.K2    = fmaf(sp[2], 0.199f, 0.001f);
    const float parLP = fmaf(sp[3], 0.8f, 0.2f);
    pr.PERC  = sp[4] * 10.0f;
    pr.UZL   = sp[5] * 100.0f;
    pr.TT    = fmaf(sp[6], 5.0f, -2.5f);
    pr.CFMAX = fmaf(sp[7], 9.5f, 0.5f);
    pr.CFRC  = (sp[8] * 0.1f) * pr.CFMAX;
    pr.CWH   = sp[9] * 0.2f;
    pr.C     = sp[10];
    const float rout_a = sp[13] * 2.9f;
    const float rout_b = sp[14] * 6.5f;
    pr.invFC   = 1.0f / pr.FC;
    pr.invLPFC = 1.0f / (parLP * pr.FC);

    // ---- routing weights (Gamma(aa)*theta^aa cancels in normalization) ----
    const float aa    = fmaxf(rout_a, 0.0f) + 0.1f;
    const float theta = fmaxf(rout_b, 0.0f) + 0.5f;
    const float am1   = aa - 1.0f;
    const float nitl2 = -LOG2E / theta;
    float w[RLEN];
    float wsum = 0.0f;
#pragma unroll
    for (int k = 0; k < RLEN; ++k) {
        const float tk = (float)k + 0.5f;
        w[k] = exp2f(am1 * __log2f(tk) + tk * nitl2);
        wsum += w[k];
    }
    const float winv = 1.0f / wsum;
#pragma unroll
    for (int k = 0; k < RLEN; ++k) w[k] *= winv;

    // ---- state ----
    float SP_ = 0.001f, MW = 0.001f, SM = 0.001f, SUZ = 0.001f, SLZ = 0.001f;
    float acc[RLEN];
#pragma unroll
    for (int k = 0; k < RLEN; ++k) acc[k] = 0.0f;

    const size_t sT = (size_t)G * 3;               // floats per time step
    const float* pF = forcing + (size_t)gc * 3;
    const float* pD = dynr    + (size_t)gc * 3;
    float* outp = out + g;

    // ---- 5 in-flight register sets (constexpr-indexed; ~30 VGPRs) ----
    F3 setF[5], setD[5];

    // ---- prologue ----
    // sets 1..4 <- G(4..7)  (ds_written at t=0..3)
    setF[1] = ld3f(pF + 4 * sT); setD[1] = ld3f(pD + 4 * sT);
    setF[2] = ld3f(pF + 5 * sT); setD[2] = ld3f(pD + 5 * sT);
    setF[3] = ld3f(pF + 6 * sT); setD[3] = ld3f(pD + 6 * sT);
    setF[4] = ld3f(pF + 7 * sT); setD[4] = ld3f(pD + 7 * sT);
    // slots 0..3 <- G(0..3) directly (one-time vmcnt stall here is fine)
#pragma unroll
    for (int r = 0; r < 4; ++r) {
        const F3 f = ld3f(pF + (size_t)r * sT);
        const F3 d = ld3f(pD + (size_t)r * sT);
        ring[r][lane][0] = f.x; ring[r][lane][1] = f.y; ring[r][lane][2] = f.z;
        ring[r][lane][3] = d.x; ring[r][lane][4] = d.y; ring[r][lane][5] = d.z;
    }

    // Step t (phase P_=t%15, set S_=t%5 — valid since 5|15):
    //  1. issue loads G(t+8) -> set S_        (first USE is the ds_write at t+4,
    //     so the load stays in flight ~4 steps; auto-vmcnt is exact)
    //  2. consume slot P_ (written at t-4), compute, store
    //  3. ds_write set (S_+1)%5 (= loads from t-4, data G(t+4)) -> slot (P_+4)%15
#define STEP(PH, FP, DP) do { \
    constexpr int P_  = (PH) % RLEN; \
    constexpr int S_  = P_ % 5; \
    constexpr int Sw_ = (P_ + 1) % 5; \
    constexpr int W_  = (P_ + 4) % RLEN; \
    setF[S_] = ld3f(FP); setD[S_] = ld3f(DP); \
    __builtin_amdgcn_sched_barrier(0); \
    const float P2_ = ring[P_][lane][0], T2_ = ring[P_][lane][1], E2_ = ring[P_][lane][2]; \
    const float x2_ = ring[P_][lane][3], y2_ = ring[P_][lane][4], z2_ = ring[P_][lane][5]; \
    const float qr_ = one_step<P_>(P2_, T2_, E2_, x2_, y2_, z2_, pr, \
                                   SP_, MW, SM, SUZ, SLZ, acc, w); \
    if (guard) __builtin_nontemporal_store(qr_, outp); \
    outp += G; \
    ring[W_][lane][0] = setF[Sw_].x; ring[W_][lane][1] = setF[Sw_].y; ring[W_][lane][2] = setF[Sw_].z; \
    ring[W_][lane][3] = setD[Sw_].x; ring[W_][lane][4] = setD[Sw_].y; ring[W_][lane][5] = setD[Sw_].z; \
} while (0)

    // ---- main: t = 0..344 (23 x 15); load rows 8..352, all in range ----
    const float* pFl = pF + 8 * sT;
    const float* pDl = pD + 8 * sT;
    for (int i = 0; i < 23; ++i) {
        STEP(0,  pFl, pDl); pFl += sT; pDl += sT;
        STEP(1,  pFl, pDl); pFl += sT; pDl += sT;
        STEP(2,  pFl, pDl); pFl += sT; pDl += sT;
        STEP(3,  pFl, pDl); pFl += sT; pDl += sT;
        STEP(4,  pFl, pDl); pFl += sT; pDl += sT;
        STEP(5,  pFl, pDl); pFl += sT; pDl += sT;
        STEP(6,  pFl, pDl); pFl += sT; pDl += sT;
        STEP(7,  pFl, pDl); pFl += sT; pDl += sT;
        STEP(8,  pFl, pDl); pFl += sT; pDl += sT;
        STEP(9,  pFl, pDl); pFl += sT; pDl += sT;
        STEP(10, pFl, pDl); pFl += sT; pDl += sT;
        STEP(11, pFl, pDl); pFl += sT; pDl += sT;
        STEP(12, pFl, pDl); pFl += sT; pDl += sT;
        STEP(13, pFl, pDl); pFl += sT; pDl += sT;
        STEP(14, pFl, pDl); pFl += sT; pDl += sT;
    }
    // ---- tail: t = 345..364; load row = min(t+8, 364) (garbage slots never read) ----
#define TROW(T) (((T) + 8 <= 364) ? ((T) + 8) : 364)
    STEP(0,  pF + (size_t)TROW(345) * sT, pD + (size_t)TROW(345) * sT);
    STEP(1,  pF + (size_t)TROW(346) * sT, pD + (size_t)TROW(346) * sT);
    STEP(2,  pF + (size_t)TROW(347) * sT, pD + (size_t)TROW(347) * sT);
    STEP(3,  pF + (size_t)TROW(348) * sT, pD + (size_t)TROW(348) * sT);
    STEP(4,  pF + (size_t)TROW(349) * sT, pD + (size_t)TROW(349) * sT);
    STEP(5,  pF + (size_t)TROW(350) * sT, pD + (size_t)TROW(350) * sT);
    STEP(6,  pF + (size_t)TROW(351) * sT, pD + (size_t)TROW(351) * sT);
    STEP(7,  pF + (size_t)TROW(352) * sT, pD + (size_t)TROW(352) * sT);
    STEP(8,  pF + (size_t)TROW(353) * sT, pD + (size_t)TROW(353) * sT);
    STEP(9,  pF + (size_t)TROW(354) * sT, pD + (size_t)TROW(354) * sT);
    STEP(10, pF + (size_t)TROW(355) * sT, pD + (size_t)TROW(355) * sT);
    STEP(11, pF + (size_t)TROW(356) * sT, pD + (size_t)TROW(356) * sT);
    STEP(12, pF + (size_t)TROW(357) * sT, pD + (size_t)TROW(357) * sT);
    STEP(13, pF + (size_t)TROW(358) * sT, pD + (size_t)TROW(358) * sT);
    STEP(14, pF + (size_t)TROW(359) * sT, pD + (size_t)TROW(359) * sT);
    STEP(0,  pF + (size_t)TROW(360) * sT, pD + (size_t)TROW(360) * sT);
    STEP(1,  pF + (size_t)TROW(361) * sT, pD + (size_t)TROW(361) * sT);
    STEP(2,  pF + (size_t)TROW(362) * sT, pD + (size_t)TROW(362) * sT);
    STEP(3,  pF + (size_t)TROW(363) * sT, pD + (size_t)TROW(363) * sT);
    STEP(4,  pF + (size_t)TROW(364) * sT, pD + (size_t)TROW(364) * sT);
#undef TROW
#undef STEP
}

extern "C" void kernel_launch(void* const* d_in, const int* in_sizes, int n_in,
                              void* d_out, int out_size, void* d_ws, size_t ws_size,
                              hipStream_t stream) {
    const float* forcing = (const float*)d_in[0];
    const float* dynr    = (const float*)d_in[1];
    const float* statr   = (const float*)d_in[2];
    float* out = (float*)d_out;

    const int G = in_sizes[2] / 15;          // static_raw (G,15); T fixed at 365
    const int block = 64;
    const int grid  = (G + block - 1) / block;
    hbv_kernel<<<grid, block, 0, stream>>>(forcing, dynr, statr, out, G);
}